// Round 1
// baseline (2592.316 us; speedup 1.0000x reference)
//
#include <hip/hip_runtime.h>
#include <stdint.h>

// ---------------------------------------------------------------------------
// Masker: 3-layer MLP head (fp32 GEMM + BatchNorm(+ReLU)) then K=1024
// Gumbel-softmax scan with z = running max.
// Round 4: gumbel scan spread over ALL 256 CUs (2 blocks per row, per-iter
// partial-sum exchange via agent-scope atomics), key chain precomputed at
// COMPILE TIME into __constant__ (no key wave), noise pipelined 2 iters ahead.
// PRNG bit-stream identical to round 3 (passed).
// ---------------------------------------------------------------------------

// ------------------------- Threefry-2x32-20 (JAX) --------------------------
__device__ __forceinline__ uint32_t rotl32(uint32_t v, int r) {
  return (v << r) | (v >> (32 - r));
}

__device__ __forceinline__ void tf2x32(uint32_t k0, uint32_t k1,
                                       uint32_t x0, uint32_t x1,
                                       uint32_t& o0, uint32_t& o1) {
  uint32_t k2 = k0 ^ k1 ^ 0x1BD11BDAu;
  x0 += k0; x1 += k1;
#define TFR(r) { x0 += x1; x1 = rotl32(x1, (r)); x1 ^= x0; }
  TFR(13) TFR(15) TFR(26) TFR(6)   x0 += k1; x1 += k2 + 1u;
  TFR(17) TFR(29) TFR(16) TFR(24)  x0 += k2; x1 += k0 + 2u;
  TFR(13) TFR(15) TFR(26) TFR(6)   x0 += k0; x1 += k1 + 3u;
  TFR(17) TFR(29) TFR(16) TFR(24)  x0 += k1; x1 += k2 + 4u;
  TFR(13) TFR(15) TFR(26) TFR(6)   x0 += k2; x1 += k0 + 5u;
#undef TFR
  o0 = x0; o1 = x1;
}

// constexpr twin: evaluates the serial split() key chain at COMPILE TIME.
constexpr uint32_t crotl(uint32_t v, int r) { return (v << r) | (v >> (32 - r)); }
struct U2 { uint32_t a, b; };
constexpr U2 ctf(uint32_t k0, uint32_t k1, uint32_t x0, uint32_t x1) {
  uint32_t k2 = k0 ^ k1 ^ 0x1BD11BDAu;
  x0 += k0; x1 += k1;
#define CTFR(r) { x0 += x1; x1 = crotl(x1, (r)); x1 ^= x0; }
  CTFR(13) CTFR(15) CTFR(26) CTFR(6)   x0 += k1; x1 += k2 + 1u;
  CTFR(17) CTFR(29) CTFR(16) CTFR(24)  x0 += k2; x1 += k0 + 2u;
  CTFR(13) CTFR(15) CTFR(26) CTFR(6)   x0 += k0; x1 += k1 + 3u;
  CTFR(17) CTFR(29) CTFR(16) CTFR(24)  x0 += k1; x1 += k2 + 4u;
  CTFR(13) CTFR(15) CTFR(26) CTFR(6)   x0 += k2; x1 += k0 + 5u;
#undef CTFR
  return {x0, x1};
}

// keys.v[2k..2k+1] = sub_k = child1 of the (k+1)-th split of key(42).
// 1026 entries: iteration k prefetches sub_{k+2} (max index 2051).
struct KeyTab { uint32_t v[2052]; };
constexpr KeyTab make_keys() {
  KeyTab t{};
  uint32_t ka = 0u, kb = 42u;   // jax.random.key(42) data = (hi=0, lo=42)
  for (int k = 0; k < 1026; ++k) {
    U2 c0 = ctf(ka, kb, 0u, 0u);   // next key
    U2 c1 = ctf(ka, kb, 0u, 1u);   // sub key
    t.v[2 * k]     = c1.a;
    t.v[2 * k + 1] = c1.b;
    ka = c0.a; kb = c0.b;
  }
  return t;
}
__constant__ KeyTab d_keys = make_keys();

// Returns g * cc where g = -ln(-ln u), cc = 2*log2(e)  (TAU=0.5).
__device__ __forceinline__ float gumbel_cc(uint32_t bits) {
  float u = __uint_as_float((bits >> 9) | 0x3f800000u) - 1.0f;
  u = fmaxf(u, 1.17549435e-38f);
  float l = __log2f(u);            // < 0
  float t = __log2f(-l);
  return fmaf(-2.0f, t, 1.0575327458538905f);
}

// ------------------------------- GEMM --------------------------------------
#define BK 16

__global__ __launch_bounds__(256) void gemm_splitk(
    const float* __restrict__ A, const float* __restrict__ W,
    float* __restrict__ P, int K, int N, int kchunk)
{
  __shared__ float sA[BK][132];
  __shared__ float sW[BK][132];
  const int tid = threadIdx.x;
  const int n0 = blockIdx.x * 128;
  const int k0 = blockIdx.y * kchunk;
  const int tx = tid & 15;
  const int ty = tid >> 4;

  float acc[8][8];
#pragma unroll
  for (int i = 0; i < 8; i++)
#pragma unroll
    for (int j = 0; j < 8; j++) acc[i][j] = 0.f;

  for (int kt = k0; kt < k0 + kchunk; kt += BK) {
#pragma unroll
    for (int i = 0; i < 2; i++) {
      int q = tid * 2 + i;
      int row = q >> 2;
      int kk = (q & 3) * 4;
      float4 av = *(const float4*)(A + (size_t)row * K + kt + kk);
      sA[kk + 0][row] = av.x; sA[kk + 1][row] = av.y;
      sA[kk + 2][row] = av.z; sA[kk + 3][row] = av.w;
      float4 wv = *(const float4*)(W + (size_t)(n0 + row) * K + kt + kk);
      sW[kk + 0][row] = wv.x; sW[kk + 1][row] = wv.y;
      sW[kk + 2][row] = wv.z; sW[kk + 3][row] = wv.w;
    }
    __syncthreads();
#pragma unroll
    for (int kk = 0; kk < BK; kk++) {
      float a[8], w[8];
#pragma unroll
      for (int i = 0; i < 8; i++) a[i] = sA[kk][ty * 8 + i];
#pragma unroll
      for (int j = 0; j < 8; j++) w[j] = sW[kk][tx * 8 + j];
#pragma unroll
      for (int i = 0; i < 8; i++)
#pragma unroll
        for (int j = 0; j < 8; j++)
          acc[i][j] = fmaf(a[i], w[j], acc[i][j]);
    }
    __syncthreads();
  }

  float* Ps = P + (size_t)blockIdx.y * 128 * N;
#pragma unroll
  for (int i = 0; i < 8; i++) {
    int b = ty * 8 + i;
#pragma unroll
    for (int j = 0; j < 8; j += 4) {
      float4 v = make_float4(acc[i][j], acc[i][j + 1], acc[i][j + 2], acc[i][j + 3]);
      *(float4*)(Ps + (size_t)b * N + n0 + tx * 8 + j) = v;
    }
  }
}

// ------------------------------ BatchNorm ----------------------------------
template <int CPB>
__global__ __launch_bounds__(256) void bn_kernel(
    const float* __restrict__ P, int nsl, int N,
    const float* __restrict__ bias, const float* __restrict__ gamma,
    const float* __restrict__ beta, float* __restrict__ out, int relu)
{
  constexpr int R = 256 / CPB;
  constexpr int NR = 128 / R;
  const int cl = threadIdx.x % CPB;
  const int rg = threadIdx.x / CPB;
  const int c = blockIdx.x * CPB + cl;
  const int r0 = rg * NR;

  float bc = bias ? bias[c] : 0.f;
  float xs[NR];
  float s = 0.f, s2 = 0.f;
#pragma unroll
  for (int i = 0; i < NR; i++) {
    float x = bc;
    for (int t = 0; t < nsl; t++)
      x += P[((size_t)t * 128 + r0 + i) * N + c];
    xs[i] = x; s += x; s2 += x * x;
  }

  __shared__ float sh_s[R][CPB], sh_s2[R][CPB];
  sh_s[rg][cl] = s; sh_s2[rg][cl] = s2;
  __syncthreads();
  float S = 0.f, S2 = 0.f;
#pragma unroll
  for (int g = 0; g < R; g++) { S += sh_s[g][cl]; S2 += sh_s2[g][cl]; }

  float mu = S * (1.f / 128.f);
  float var = S2 * (1.f / 128.f) - mu * mu;
  float rstd = rsqrtf(var + 1e-5f);
  float ga = gamma ? gamma[c] : 1.f;
  float be = beta ? beta[c] : 0.f;
  float scale = rstd * ga;
  float shift = be - mu * scale;
#pragma unroll
  for (int i = 0; i < NR; i++) {
    float y = fmaf(xs[i], scale, shift);
    if (relu) y = fmaxf(y, 0.f);
    out[(size_t)(r0 + i) * N + c] = y;
  }
}

// ----------------------------- Gumbel scan ---------------------------------
// 256 blocks x 1024 threads: blocks b and b^128 each own one half (1024 cols)
// of row b&127 -> every CU gets a block (16 waves = 4/SIMD). Per iteration
// each block computes its half-row sum, publishes it to a per-iteration slot
// (relaxed agent-scope store; the positive value doubles as the ready flag),
// generates the Gumbel noise for iteration k+2 (hides the exchange latency),
// then polls the partner slot. Pair b<->b^128 lands on the same XCD (128%8==0).
// Sub-keys come from the compile-time __constant__ table (no key wave).
__global__ __launch_bounds__(1024) void gumbel_kernel(
    const float* __restrict__ logits, float* __restrict__ z_out,
    uint32_t* __restrict__ slots)   // [1024][128][2], pre-zeroed
{
  const int tid  = threadIdx.x;
  const int row  = blockIdx.x & 127;
  const int half = blockIdx.x >> 7;
  const int wid  = tid >> 6;
  const int lane = tid & 63;
  const int col  = half * 1024 + tid;
  const uint32_t idx = (uint32_t)(row * 2048 + col);

  __shared__ float s_sum[2][16];
  const float cc = 2.8853900817779268f;   // 2*log2(e)

  float mask = logits[row * 2048 + col];
  float zacc = 0.f;
  uint32_t b0, b1;
  tf2x32(d_keys.v[0], d_keys.v[1], 0u, idx, b0, b1);
  float g_cur = gumbel_cc(b0 ^ b1);       // g_0 * cc
  tf2x32(d_keys.v[2], d_keys.v[3], 0u, idx, b0, b1);
  float g_nxt = gumbel_cc(b0 ^ b1);       // g_1 * cc

  for (int k = 0; k < 1024; ++k) {
    const int p = k & 1;
    // exp((mask+g)/TAU) in log2 domain; exponent <= ~81 -> no overflow,
    // >= ~-48 -> sum never 0 (slot flag is safe).
    float e = exp2f(fmaf(mask, cc, g_cur));
    float ss = e;
#pragma unroll
    for (int off = 1; off < 64; off <<= 1)
      ss += __shfl_xor(ss, off, 64);
    if (lane == 0) s_sum[p][wid] = ss;

    const uint32_t ska = d_keys.v[2 * k + 4];   // sub_{k+2}
    const uint32_t skb = d_keys.v[2 * k + 5];
    __syncthreads();

    float local = 0.f;
#pragma unroll
    for (int w = 0; w < 16; ++w) local += s_sum[p][w];

    const size_t sidx = ((size_t)k * 128 + row) * 2;
    if (tid == 0)
      __hip_atomic_store(slots + sidx + half, __float_as_uint(local),
                         __ATOMIC_RELAXED, __HIP_MEMORY_SCOPE_AGENT);

    // noise for iteration k+2 — independent work hiding the exchange
    tf2x32(ska, skb, 0u, idx, b0, b1);
    float g_new = gumbel_cc(b0 ^ b1);

    uint32_t ov;
    do {
      ov = __hip_atomic_load(slots + sidx + (half ^ 1),
                             __ATOMIC_RELAXED, __HIP_MEMORY_SCOPE_AGENT);
    } while (ov == 0u);

    float S = local + __uint_as_float(ov);
    float r = 1.0f / S;
    float m = e * r;
    mask = m;
    zacc = fmaxf(zacc, m);
    g_cur = g_nxt; g_nxt = g_new;
  }

  z_out[row * 2048 + col] = zacc;
}

// ------------------------------- launch ------------------------------------
extern "C" void kernel_launch(void* const* d_in, const int* in_sizes, int n_in,
                              void* d_out, int out_size, void* d_ws, size_t ws_size,
                              hipStream_t stream)
{
  const float* f   = (const float*)d_in[0];
  const float* w1  = (const float*)d_in[1];
  const float* b1  = (const float*)d_in[2];
  const float* g1  = (const float*)d_in[3];
  const float* be1 = (const float*)d_in[4];
  const float* w2  = (const float*)d_in[5];
  const float* b2  = (const float*)d_in[6];
  const float* g2  = (const float*)d_in[7];
  const float* be2 = (const float*)d_in[8];
  const float* w3  = (const float*)d_in[9];
  const float* b3  = (const float*)d_in[10];
  float* out = (float*)d_out;

  // ws layout (floats): h1 (4MB) | h2 (4MB) | logits (1MB) | P
  // slots (1MB) aliases h1 — h1 is dead after gemm2 consumes it.
  float* h1     = (float*)d_ws;
  float* h2     = h1 + 1048576;
  float* logits = h2 + 1048576;
  float* P      = logits + 262144;
  uint32_t* slots = (uint32_t*)h1;

  const size_t need_big = (size_t)(2359296 + 8388608) * 4;
  const int s12 = (ws_size >= need_big) ? 8 : 4;
  const int s3  = (ws_size >= need_big) ? 32 : 16;

  dim3 blk(256);
  // layer 1: (128,2048) @ (8192,2048)^T
  gemm_splitk<<<dim3(64, s12), blk, 0, stream>>>(f, w1, P, 2048, 8192, 2048 / s12);
  bn_kernel<64><<<dim3(128), blk, 0, stream>>>(P, s12, 8192, b1, g1, be1, h1, 1);
  // layer 2: (128,8192) @ (8192,8192)^T
  gemm_splitk<<<dim3(64, s12), blk, 0, stream>>>(h1, w2, P, 8192, 8192, 8192 / s12);
  // h1 is no longer needed -> zero the exchange slots (stream-ordered).
  hipMemsetAsync(slots, 0, (size_t)1024 * 128 * 2 * sizeof(uint32_t), stream);
  bn_kernel<64><<<dim3(128), blk, 0, stream>>>(P, s12, 8192, b2, g2, be2, h2, 1);
  // layer 3: (128,8192) @ (2048,8192)^T, BN no affine
  gemm_splitk<<<dim3(16, s3), blk, 0, stream>>>(h2, w3, P, 8192, 2048, 8192 / s3);
  bn_kernel<32><<<dim3(64), blk, 0, stream>>>(P, s3, 2048, b3, nullptr, nullptr, logits, 0);
  // gumbel-softmax scan, K=1024, 2 blocks per row
  gumbel_kernel<<<dim3(256), dim3(1024), 0, stream>>>(logits, out, slots);
}

// Round 2
// 2143.338 us; speedup vs baseline: 1.2095x; 1.2095x over previous
//
#include <hip/hip_runtime.h>
#include <stdint.h>

// ---------------------------------------------------------------------------
// Masker: 3-layer MLP head (fp32 GEMM + BatchNorm(+ReLU)) then K=1024
// Gumbel-softmax scan with z = running max.
// Round 5: scan split into producer/consumer. Threefry noise (the only
// iteration-independent work, ~75% of scan VALU) is precomputed by a
// full-chip noise_kernel into the dead P region in windows of T iterations;
// the serial scan_kernel is back to ONE block per row (no cross-block
// exchange — round 4 showed the global exchange lengthens the critical
// path), 2 cols/thread, 1 barrier/iter, noise prefetched 2 iters ahead.
// PRNG bit-stream identical to rounds 3/4 (both passed).
// ---------------------------------------------------------------------------

// ------------------------- Threefry-2x32-20 (JAX) --------------------------
__device__ __forceinline__ uint32_t rotl32(uint32_t v, int r) {
  return (v << r) | (v >> (32 - r));
}

__device__ __forceinline__ void tf2x32(uint32_t k0, uint32_t k1,
                                       uint32_t x0, uint32_t x1,
                                       uint32_t& o0, uint32_t& o1) {
  uint32_t k2 = k0 ^ k1 ^ 0x1BD11BDAu;
  x0 += k0; x1 += k1;
#define TFR(r) { x0 += x1; x1 = rotl32(x1, (r)); x1 ^= x0; }
  TFR(13) TFR(15) TFR(26) TFR(6)   x0 += k1; x1 += k2 + 1u;
  TFR(17) TFR(29) TFR(16) TFR(24)  x0 += k2; x1 += k0 + 2u;
  TFR(13) TFR(15) TFR(26) TFR(6)   x0 += k0; x1 += k1 + 3u;
  TFR(17) TFR(29) TFR(16) TFR(24)  x0 += k1; x1 += k2 + 4u;
  TFR(13) TFR(15) TFR(26) TFR(6)   x0 += k2; x1 += k0 + 5u;
#undef TFR
  o0 = x0; o1 = x1;
}

// constexpr twin: evaluates the serial split() key chain at COMPILE TIME.
constexpr uint32_t crotl(uint32_t v, int r) { return (v << r) | (v >> (32 - r)); }
struct U2 { uint32_t a, b; };
constexpr U2 ctf(uint32_t k0, uint32_t k1, uint32_t x0, uint32_t x1) {
  uint32_t k2 = k0 ^ k1 ^ 0x1BD11BDAu;
  x0 += k0; x1 += k1;
#define CTFR(r) { x0 += x1; x1 = crotl(x1, (r)); x1 ^= x0; }
  CTFR(13) CTFR(15) CTFR(26) CTFR(6)   x0 += k1; x1 += k2 + 1u;
  CTFR(17) CTFR(29) CTFR(16) CTFR(24)  x0 += k2; x1 += k0 + 2u;
  CTFR(13) CTFR(15) CTFR(26) CTFR(6)   x0 += k0; x1 += k1 + 3u;
  CTFR(17) CTFR(29) CTFR(16) CTFR(24)  x0 += k1; x1 += k2 + 4u;
  CTFR(13) CTFR(15) CTFR(26) CTFR(6)   x0 += k2; x1 += k0 + 5u;
#undef CTFR
  return {x0, x1};
}

// keys.v[2k..2k+1] = sub_k = child1 of the (k+1)-th split of key(42).
struct KeyTab { uint32_t v[2052]; };
constexpr KeyTab make_keys() {
  KeyTab t{};
  uint32_t ka = 0u, kb = 42u;   // jax.random.key(42)
  for (int k = 0; k < 1026; ++k) {
    U2 c0 = ctf(ka, kb, 0u, 0u);   // next key
    U2 c1 = ctf(ka, kb, 0u, 1u);   // sub key
    t.v[2 * k]     = c1.a;
    t.v[2 * k + 1] = c1.b;
    ka = c0.a; kb = c0.b;
  }
  return t;
}
__constant__ KeyTab d_keys = make_keys();

// Returns g * cc where g = -ln(-ln u), cc = 2*log2(e)  (TAU=0.5).
__device__ __forceinline__ float gumbel_cc(uint32_t bits) {
  float u = __uint_as_float((bits >> 9) | 0x3f800000u) - 1.0f;
  u = fmaxf(u, 1.17549435e-38f);
  float l = __log2f(u);            // < 0
  float t = __log2f(-l);
  return fmaf(-2.0f, t, 1.0575327458538905f);
}

// ------------------------------- GEMM --------------------------------------
#define BK 16

__global__ __launch_bounds__(256) void gemm_splitk(
    const float* __restrict__ A, const float* __restrict__ W,
    float* __restrict__ P, int K, int N, int kchunk)
{
  __shared__ float sA[BK][132];
  __shared__ float sW[BK][132];
  const int tid = threadIdx.x;
  const int n0 = blockIdx.x * 128;
  const int k0 = blockIdx.y * kchunk;
  const int tx = tid & 15;
  const int ty = tid >> 4;

  float acc[8][8];
#pragma unroll
  for (int i = 0; i < 8; i++)
#pragma unroll
    for (int j = 0; j < 8; j++) acc[i][j] = 0.f;

  for (int kt = k0; kt < k0 + kchunk; kt += BK) {
#pragma unroll
    for (int i = 0; i < 2; i++) {
      int q = tid * 2 + i;
      int row = q >> 2;
      int kk = (q & 3) * 4;
      float4 av = *(const float4*)(A + (size_t)row * K + kt + kk);
      sA[kk + 0][row] = av.x; sA[kk + 1][row] = av.y;
      sA[kk + 2][row] = av.z; sA[kk + 3][row] = av.w;
      float4 wv = *(const float4*)(W + (size_t)(n0 + row) * K + kt + kk);
      sW[kk + 0][row] = wv.x; sW[kk + 1][row] = wv.y;
      sW[kk + 2][row] = wv.z; sW[kk + 3][row] = wv.w;
    }
    __syncthreads();
#pragma unroll
    for (int kk = 0; kk < BK; kk++) {
      float a[8], w[8];
#pragma unroll
      for (int i = 0; i < 8; i++) a[i] = sA[kk][ty * 8 + i];
#pragma unroll
      for (int j = 0; j < 8; j++) w[j] = sW[kk][tx * 8 + j];
#pragma unroll
      for (int i = 0; i < 8; i++)
#pragma unroll
        for (int j = 0; j < 8; j++)
          acc[i][j] = fmaf(a[i], w[j], acc[i][j]);
    }
    __syncthreads();
  }

  float* Ps = P + (size_t)blockIdx.y * 128 * N;
#pragma unroll
  for (int i = 0; i < 8; i++) {
    int b = ty * 8 + i;
#pragma unroll
    for (int j = 0; j < 8; j += 4) {
      float4 v = make_float4(acc[i][j], acc[i][j + 1], acc[i][j + 2], acc[i][j + 3]);
      *(float4*)(Ps + (size_t)b * N + n0 + tx * 8 + j) = v;
    }
  }
}

// ------------------------------ BatchNorm ----------------------------------
template <int CPB>
__global__ __launch_bounds__(256) void bn_kernel(
    const float* __restrict__ P, int nsl, int N,
    const float* __restrict__ bias, const float* __restrict__ gamma,
    const float* __restrict__ beta, float* __restrict__ out, int relu)
{
  constexpr int R = 256 / CPB;
  constexpr int NR = 128 / R;
  const int cl = threadIdx.x % CPB;
  const int rg = threadIdx.x / CPB;
  const int c = blockIdx.x * CPB + cl;
  const int r0 = rg * NR;

  float bc = bias ? bias[c] : 0.f;
  float xs[NR];
  float s = 0.f, s2 = 0.f;
#pragma unroll
  for (int i = 0; i < NR; i++) {
    float x = bc;
    for (int t = 0; t < nsl; t++)
      x += P[((size_t)t * 128 + r0 + i) * N + c];
    xs[i] = x; s += x; s2 += x * x;
  }

  __shared__ float sh_s[R][CPB], sh_s2[R][CPB];
  sh_s[rg][cl] = s; sh_s2[rg][cl] = s2;
  __syncthreads();
  float S = 0.f, S2 = 0.f;
#pragma unroll
  for (int g = 0; g < R; g++) { S += sh_s[g][cl]; S2 += sh_s2[g][cl]; }

  float mu = S * (1.f / 128.f);
  float var = S2 * (1.f / 128.f) - mu * mu;
  float rstd = rsqrtf(var + 1e-5f);
  float ga = gamma ? gamma[c] : 1.f;
  float be = beta ? beta[c] : 0.f;
  float scale = rstd * ga;
  float shift = be - mu * scale;
#pragma unroll
  for (int i = 0; i < NR; i++) {
    float y = fmaf(xs[i], scale, shift);
    if (relu) y = fmaxf(y, 0.f);
    out[(size_t)(r0 + i) * N + c] = y;
  }
}

// ---------------------------- Noise producer -------------------------------
// Fully parallel: gcc(k,row,col) depends only on (k, row*2048+col). Fills
// nbuf[kk][row][col] for kk in [0,T). Grid = T*128 blocks, 256 thr, 8 cols
// each (two coalesced float4 stores: cols [4t,4t+4) and [1024+4t,1024+4t+4)).
__global__ __launch_bounds__(256) void noise_kernel(
    float* __restrict__ nbuf, int k0, int T)
{
  const int kk  = blockIdx.x >> 7;     // 0..T-1
  const int row = blockIdx.x & 127;
  const int k   = k0 + kk;
  const uint32_t ka = d_keys.v[2 * k], kb = d_keys.v[2 * k + 1];
  const int c0 = threadIdx.x * 4;
  float* base = nbuf + (size_t)kk * 262144 + row * 2048;
  uint32_t b0, b1;
  float4 v;
  uint32_t idx = (uint32_t)(row * 2048 + c0);
  tf2x32(ka, kb, 0u, idx + 0u, b0, b1); v.x = gumbel_cc(b0 ^ b1);
  tf2x32(ka, kb, 0u, idx + 1u, b0, b1); v.y = gumbel_cc(b0 ^ b1);
  tf2x32(ka, kb, 0u, idx + 2u, b0, b1); v.z = gumbel_cc(b0 ^ b1);
  tf2x32(ka, kb, 0u, idx + 3u, b0, b1); v.w = gumbel_cc(b0 ^ b1);
  *(float4*)(base + c0) = v;
  idx += 1024u;
  tf2x32(ka, kb, 0u, idx + 0u, b0, b1); v.x = gumbel_cc(b0 ^ b1);
  tf2x32(ka, kb, 0u, idx + 1u, b0, b1); v.y = gumbel_cc(b0 ^ b1);
  tf2x32(ka, kb, 0u, idx + 2u, b0, b1); v.z = gumbel_cc(b0 ^ b1);
  tf2x32(ka, kb, 0u, idx + 3u, b0, b1); v.w = gumbel_cc(b0 ^ b1);
  *(float4*)(base + 1024 + c0) = v;
}

// ----------------------------- Scan consumer -------------------------------
// One block per row (no cross-block traffic). 1024 threads, 2 adjacent cols
// each (float2). Per iter: exp2, 64-lane xor-reduce, lane0->LDS, ONE barrier,
// 16-wide pairwise LDS sum, 1/S, update mask/z. Noise prefetched 2 iters
// ahead (static registers, no runtime-indexed arrays). State in d_ws.
__global__ __launch_bounds__(1024) void scan_kernel(
    const float* __restrict__ nbuf, int T,
    const float* __restrict__ msrc, float* __restrict__ mdst,
    float* __restrict__ zst, float* __restrict__ zout,
    int first, int last)
{
  const int tid = threadIdx.x;
  const int row = blockIdx.x;
  const int wid = tid >> 6, lane = tid & 63;
  __shared__ float s_sum[2][16];
  const float cc = 2.8853900817779268f;   // 2*log2(e)
  const size_t off = (size_t)row * 2048 + tid * 2;

  float2 mv = *(const float2*)(msrc + off);
  float m0 = mv.x, m1 = mv.y;
  float z0 = 0.f, z1 = 0.f;
  if (!first) { float2 zv = *(const float2*)(zst + off); z0 = zv.x; z1 = zv.y; }

  const float2* np = (const float2*)(nbuf + off);  // stride 131072 float2/iter
  float2 na = np[0];
  float2 nb = np[131072];

  for (int kk = 0; kk < T; kk += 2) {
    {  // even iteration: slot 0, uses na, prefetches kk+2
      float e0 = exp2f(fmaf(m0, cc, na.x));
      float e1 = exp2f(fmaf(m1, cc, na.y));
      float ss = e0 + e1;
#pragma unroll
      for (int o = 1; o < 64; o <<= 1) ss += __shfl_xor(ss, o, 64);
      if (lane == 0) s_sum[0][wid] = ss;
      if (kk + 2 < T) na = np[(size_t)(kk + 2) * 131072];
      __syncthreads();
      const float4* sp = (const float4*)&s_sum[0][0];
      float4 q0 = sp[0], q1 = sp[1], q2 = sp[2], q3 = sp[3];
      float S = (((q0.x + q0.y) + (q0.z + q0.w)) + ((q1.x + q1.y) + (q1.z + q1.w)))
              + (((q2.x + q2.y) + (q2.z + q2.w)) + ((q3.x + q3.y) + (q3.z + q3.w)));
      float r = 1.0f / S;
      m0 = e0 * r; m1 = e1 * r;
      z0 = fmaxf(z0, m0); z1 = fmaxf(z1, m1);
    }
    {  // odd iteration: slot 1, uses nb, prefetches kk+3
      float e0 = exp2f(fmaf(m0, cc, nb.x));
      float e1 = exp2f(fmaf(m1, cc, nb.y));
      float ss = e0 + e1;
#pragma unroll
      for (int o = 1; o < 64; o <<= 1) ss += __shfl_xor(ss, o, 64);
      if (lane == 0) s_sum[1][wid] = ss;
      if (kk + 3 < T) nb = np[(size_t)(kk + 3) * 131072];
      __syncthreads();
      const float4* sp = (const float4*)&s_sum[1][0];
      float4 q0 = sp[0], q1 = sp[1], q2 = sp[2], q3 = sp[3];
      float S = (((q0.x + q0.y) + (q0.z + q0.w)) + ((q1.x + q1.y) + (q1.z + q1.w)))
              + (((q2.x + q2.y) + (q2.z + q2.w)) + ((q3.x + q3.y) + (q3.z + q3.w)));
      float r = 1.0f / S;
      m0 = e0 * r; m1 = e1 * r;
      z0 = fmaxf(z0, m0); z1 = fmaxf(z1, m1);
    }
  }

  if (last) {
    *(float2*)(zout + off) = make_float2(z0, z1);
  } else {
    *(float2*)(mdst + off) = make_float2(m0, m1);
    *(float2*)(zst + off)  = make_float2(z0, z1);
  }
}

// ------------------------------- launch ------------------------------------
extern "C" void kernel_launch(void* const* d_in, const int* in_sizes, int n_in,
                              void* d_out, int out_size, void* d_ws, size_t ws_size,
                              hipStream_t stream)
{
  const float* f   = (const float*)d_in[0];
  const float* w1  = (const float*)d_in[1];
  const float* b1  = (const float*)d_in[2];
  const float* g1  = (const float*)d_in[3];
  const float* be1 = (const float*)d_in[4];
  const float* w2  = (const float*)d_in[5];
  const float* b2  = (const float*)d_in[6];
  const float* g2  = (const float*)d_in[7];
  const float* be2 = (const float*)d_in[8];
  const float* w3  = (const float*)d_in[9];
  const float* b3  = (const float*)d_in[10];
  float* out = (float*)d_out;

  // ws layout (floats): h1 (4MB) | h2 (4MB) | logits (1MB) | P (s12 MB*4)
  float* h1     = (float*)d_ws;
  float* h2     = h1 + 1048576;
  float* logits = h2 + 1048576;
  float* P      = logits + 262144;

  const size_t need_big = (size_t)(2359296 + 8388608) * 4;
  const int s12 = (ws_size >= need_big) ? 8 : 4;
  const int s3  = (ws_size >= need_big) ? 32 : 16;

  dim3 blk(256);
  // layer 1: (128,2048) @ (8192,2048)^T
  gemm_splitk<<<dim3(64, s12), blk, 0, stream>>>(f, w1, P, 2048, 8192, 2048 / s12);
  bn_kernel<64><<<dim3(128), blk, 0, stream>>>(P, s12, 8192, b1, g1, be1, h1, 1);
  // layer 2: (128,8192) @ (8192,8192)^T
  gemm_splitk<<<dim3(64, s12), blk, 0, stream>>>(h1, w2, P, 8192, 8192, 8192 / s12);
  bn_kernel<64><<<dim3(128), blk, 0, stream>>>(P, s12, 8192, b2, g2, be2, h2, 1);
  // layer 3: (128,8192) @ (2048,8192)^T, BN no affine
  gemm_splitk<<<dim3(16, s3), blk, 0, stream>>>(h2, w3, P, 8192, 2048, 8192 / s3);
  bn_kernel<32><<<dim3(64), blk, 0, stream>>>(P, s3, 2048, b3, nullptr, nullptr, logits, 0);

  // ---- gumbel scan, chunked producer/consumer ----
  // overlays on dead regions: mask/zacc state in h1 (dead after gemm2),
  // noise window in P..end-of-ws (dead after bn3).
  float* mstate = h1;             // 262144 floats
  float* zstate = h1 + 262144;    // 262144 floats
  float* nbuf   = P;
  size_t avail_f = ws_size / 4 - 2359296;          // floats from P to ws end
  int T = (int)(avail_f / 262144);                 // iters per window (>=16)
  if (T > 1024) T = 1024;
  T &= ~1;
  for (int k0 = 0; k0 < 1024; ) {
    int t = T; if (t > 1024 - k0) t = 1024 - k0;
    t &= ~1;
    noise_kernel<<<dim3(t * 128), dim3(256), 0, stream>>>(nbuf, k0, t);
    const int first = (k0 == 0);
    const int lastc = (k0 + t >= 1024);
    scan_kernel<<<dim3(128), dim3(1024), 0, stream>>>(
        nbuf, t, first ? logits : mstate, mstate, zstate, out, first, lastc);
    k0 += t;
  }
}

// Round 3
// 1841.348 us; speedup vs baseline: 1.4078x; 1.1640x over previous
//
#include <hip/hip_runtime.h>
#include <stdint.h>

// ---------------------------------------------------------------------------
// Masker: 3-layer MLP head (fp32 GEMM + BatchNorm(+ReLU)) then K=1024
// Gumbel-softmax scan with z = running max.
// Round 6: scan reduction restructured. Round-5 counters showed the scan is
// LDS-pipe-bound (1024 thr x (6 ds_swizzle + 4 ds_read_b128)/iter ~1350
// cy/iter on the DS pipe). Now: 256 thr/block (4 waves), 8 cols/thread,
// per-thread tree sum + DPP wave reduce (VALU pipe, ~48 cy) + ONE LDS
// float4 broadcast per iter; noise prefetched 4 iters deep. Producer
// noise_kernel and chunking unchanged. PRNG bit-stream identical to
// rounds 3/4/5 (all passed).
// ---------------------------------------------------------------------------

// ------------------------- Threefry-2x32-20 (JAX) --------------------------
__device__ __forceinline__ uint32_t rotl32(uint32_t v, int r) {
  return (v << r) | (v >> (32 - r));
}

__device__ __forceinline__ void tf2x32(uint32_t k0, uint32_t k1,
                                       uint32_t x0, uint32_t x1,
                                       uint32_t& o0, uint32_t& o1) {
  uint32_t k2 = k0 ^ k1 ^ 0x1BD11BDAu;
  x0 += k0; x1 += k1;
#define TFR(r) { x0 += x1; x1 = rotl32(x1, (r)); x1 ^= x0; }
  TFR(13) TFR(15) TFR(26) TFR(6)   x0 += k1; x1 += k2 + 1u;
  TFR(17) TFR(29) TFR(16) TFR(24)  x0 += k2; x1 += k0 + 2u;
  TFR(13) TFR(15) TFR(26) TFR(6)   x0 += k0; x1 += k1 + 3u;
  TFR(17) TFR(29) TFR(16) TFR(24)  x0 += k1; x1 += k2 + 4u;
  TFR(13) TFR(15) TFR(26) TFR(6)   x0 += k2; x1 += k0 + 5u;
#undef TFR
  o0 = x0; o1 = x1;
}

// constexpr twin: evaluates the serial split() key chain at COMPILE TIME.
constexpr uint32_t crotl(uint32_t v, int r) { return (v << r) | (v >> (32 - r)); }
struct U2 { uint32_t a, b; };
constexpr U2 ctf(uint32_t k0, uint32_t k1, uint32_t x0, uint32_t x1) {
  uint32_t k2 = k0 ^ k1 ^ 0x1BD11BDAu;
  x0 += k0; x1 += k1;
#define CTFR(r) { x0 += x1; x1 = crotl(x1, (r)); x1 ^= x0; }
  CTFR(13) CTFR(15) CTFR(26) CTFR(6)   x0 += k1; x1 += k2 + 1u;
  CTFR(17) CTFR(29) CTFR(16) CTFR(24)  x0 += k2; x1 += k0 + 2u;
  CTFR(13) CTFR(15) CTFR(26) CTFR(6)   x0 += k0; x1 += k1 + 3u;
  CTFR(17) CTFR(29) CTFR(16) CTFR(24)  x0 += k1; x1 += k2 + 4u;
  CTFR(13) CTFR(15) CTFR(26) CTFR(6)   x0 += k2; x1 += k0 + 5u;
#undef CTFR
  return {x0, x1};
}

// keys.v[2k..2k+1] = sub_k = child1 of the (k+1)-th split of key(42).
struct KeyTab { uint32_t v[2052]; };
constexpr KeyTab make_keys() {
  KeyTab t{};
  uint32_t ka = 0u, kb = 42u;   // jax.random.key(42)
  for (int k = 0; k < 1026; ++k) {
    U2 c0 = ctf(ka, kb, 0u, 0u);   // next key
    U2 c1 = ctf(ka, kb, 0u, 1u);   // sub key
    t.v[2 * k]     = c1.a;
    t.v[2 * k + 1] = c1.b;
    ka = c0.a; kb = c0.b;
  }
  return t;
}
__constant__ KeyTab d_keys = make_keys();

// Returns g * cc where g = -ln(-ln u), cc = 2*log2(e)  (TAU=0.5).
__device__ __forceinline__ float gumbel_cc(uint32_t bits) {
  float u = __uint_as_float((bits >> 9) | 0x3f800000u) - 1.0f;
  u = fmaxf(u, 1.17549435e-38f);
  float l = __log2f(u);            // < 0
  float t = __log2f(-l);
  return fmaf(-2.0f, t, 1.0575327458538905f);
}

// fast exp2/rcp (<=1 ulp; exponent range here is [-7, 51] -> safe)
#if __has_builtin(__builtin_amdgcn_exp2f)
#define EXP2F(x) __builtin_amdgcn_exp2f(x)
#else
#define EXP2F(x) exp2f(x)
#endif
#if __has_builtin(__builtin_amdgcn_rcpf)
#define RCPF(x) __builtin_amdgcn_rcpf(x)
#else
#define RCPF(x) (1.0f / (x))
#endif

// ------------------------------- GEMM --------------------------------------
#define BK 16

__global__ __launch_bounds__(256) void gemm_splitk(
    const float* __restrict__ A, const float* __restrict__ W,
    float* __restrict__ P, int K, int N, int kchunk)
{
  __shared__ float sA[BK][132];
  __shared__ float sW[BK][132];
  const int tid = threadIdx.x;
  const int n0 = blockIdx.x * 128;
  const int k0 = blockIdx.y * kchunk;
  const int tx = tid & 15;
  const int ty = tid >> 4;

  float acc[8][8];
#pragma unroll
  for (int i = 0; i < 8; i++)
#pragma unroll
    for (int j = 0; j < 8; j++) acc[i][j] = 0.f;

  for (int kt = k0; kt < k0 + kchunk; kt += BK) {
#pragma unroll
    for (int i = 0; i < 2; i++) {
      int q = tid * 2 + i;
      int row = q >> 2;
      int kk = (q & 3) * 4;
      float4 av = *(const float4*)(A + (size_t)row * K + kt + kk);
      sA[kk + 0][row] = av.x; sA[kk + 1][row] = av.y;
      sA[kk + 2][row] = av.z; sA[kk + 3][row] = av.w;
      float4 wv = *(const float4*)(W + (size_t)(n0 + row) * K + kt + kk);
      sW[kk + 0][row] = wv.x; sW[kk + 1][row] = wv.y;
      sW[kk + 2][row] = wv.z; sW[kk + 3][row] = wv.w;
    }
    __syncthreads();
#pragma unroll
    for (int kk = 0; kk < BK; kk++) {
      float a[8], w[8];
#pragma unroll
      for (int i = 0; i < 8; i++) a[i] = sA[kk][ty * 8 + i];
#pragma unroll
      for (int j = 0; j < 8; j++) w[j] = sW[kk][tx * 8 + j];
#pragma unroll
      for (int i = 0; i < 8; i++)
#pragma unroll
        for (int j = 0; j < 8; j++)
          acc[i][j] = fmaf(a[i], w[j], acc[i][j]);
    }
    __syncthreads();
  }

  float* Ps = P + (size_t)blockIdx.y * 128 * N;
#pragma unroll
  for (int i = 0; i < 8; i++) {
    int b = ty * 8 + i;
#pragma unroll
    for (int j = 0; j < 8; j += 4) {
      float4 v = make_float4(acc[i][j], acc[i][j + 1], acc[i][j + 2], acc[i][j + 3]);
      *(float4*)(Ps + (size_t)b * N + n0 + tx * 8 + j) = v;
    }
  }
}

// ------------------------------ BatchNorm ----------------------------------
template <int CPB>
__global__ __launch_bounds__(256) void bn_kernel(
    const float* __restrict__ P, int nsl, int N,
    const float* __restrict__ bias, const float* __restrict__ gamma,
    const float* __restrict__ beta, float* __restrict__ out, int relu)
{
  constexpr int R = 256 / CPB;
  constexpr int NR = 128 / R;
  const int cl = threadIdx.x % CPB;
  const int rg = threadIdx.x / CPB;
  const int c = blockIdx.x * CPB + cl;
  const int r0 = rg * NR;

  float bc = bias ? bias[c] : 0.f;
  float xs[NR];
  float s = 0.f, s2 = 0.f;
#pragma unroll
  for (int i = 0; i < NR; i++) {
    float x = bc;
    for (int t = 0; t < nsl; t++)
      x += P[((size_t)t * 128 + r0 + i) * N + c];
    xs[i] = x; s += x; s2 += x * x;
  }

  __shared__ float sh_s[R][CPB], sh_s2[R][CPB];
  sh_s[rg][cl] = s; sh_s2[rg][cl] = s2;
  __syncthreads();
  float S = 0.f, S2 = 0.f;
#pragma unroll
  for (int g = 0; g < R; g++) { S += sh_s[g][cl]; S2 += sh_s2[g][cl]; }

  float mu = S * (1.f / 128.f);
  float var = S2 * (1.f / 128.f) - mu * mu;
  float rstd = rsqrtf(var + 1e-5f);
  float ga = gamma ? gamma[c] : 1.f;
  float be = beta ? beta[c] : 0.f;
  float scale = rstd * ga;
  float shift = be - mu * scale;
#pragma unroll
  for (int i = 0; i < NR; i++) {
    float y = fmaf(xs[i], scale, shift);
    if (relu) y = fmaxf(y, 0.f);
    out[(size_t)(r0 + i) * N + c] = y;
  }
}

// ---------------------------- Noise producer -------------------------------
__global__ __launch_bounds__(256) void noise_kernel(
    float* __restrict__ nbuf, int k0, int T)
{
  const int kk  = blockIdx.x >> 7;     // 0..T-1
  const int row = blockIdx.x & 127;
  const int k   = k0 + kk;
  const uint32_t ka = d_keys.v[2 * k], kb = d_keys.v[2 * k + 1];
  const int c0 = threadIdx.x * 4;
  float* base = nbuf + (size_t)kk * 262144 + row * 2048;
  uint32_t b0, b1;
  float4 v;
  uint32_t idx = (uint32_t)(row * 2048 + c0);
  tf2x32(ka, kb, 0u, idx + 0u, b0, b1); v.x = gumbel_cc(b0 ^ b1);
  tf2x32(ka, kb, 0u, idx + 1u, b0, b1); v.y = gumbel_cc(b0 ^ b1);
  tf2x32(ka, kb, 0u, idx + 2u, b0, b1); v.z = gumbel_cc(b0 ^ b1);
  tf2x32(ka, kb, 0u, idx + 3u, b0, b1); v.w = gumbel_cc(b0 ^ b1);
  *(float4*)(base + c0) = v;
  idx += 1024u;
  tf2x32(ka, kb, 0u, idx + 0u, b0, b1); v.x = gumbel_cc(b0 ^ b1);
  tf2x32(ka, kb, 0u, idx + 1u, b0, b1); v.y = gumbel_cc(b0 ^ b1);
  tf2x32(ka, kb, 0u, idx + 2u, b0, b1); v.z = gumbel_cc(b0 ^ b1);
  tf2x32(ka, kb, 0u, idx + 3u, b0, b1); v.w = gumbel_cc(b0 ^ b1);
  *(float4*)(base + 1024 + c0) = v;
}

// -------------------------- DPP wave reduction -----------------------------
// Canonical GCN wave64 sum: after the chain, lane 63 holds the wave total.
// update_dpp(old=0,...): lanes with invalid source / masked rows contribute 0.
template <int CTRL, int RMASK>
__device__ __forceinline__ float dpp_addstep(float v) {
  int t = __builtin_amdgcn_update_dpp(0, __float_as_int(v), CTRL, RMASK, 0xF, false);
  return v + __int_as_float(t);
}
__device__ __forceinline__ float wave_sum_dpp(float p) {
  p = dpp_addstep<0x111, 0xF>(p);   // row_shr:1
  p = dpp_addstep<0x112, 0xF>(p);   // row_shr:2
  p = dpp_addstep<0x114, 0xF>(p);   // row_shr:4
  p = dpp_addstep<0x118, 0xF>(p);   // row_shr:8  -> lane15 of each row16
  p = dpp_addstep<0x142, 0xA>(p);   // row_bcast:15 -> lane31/63 have 32-sums
  p = dpp_addstep<0x143, 0xC>(p);   // row_bcast:31 -> lane63 has wave sum
  return p;
}

// ----------------------------- Scan consumer -------------------------------
// One block per row, 256 threads (4 waves), 8 contiguous cols/thread.
// Per iter: 8x exp2 + tree sum (VALU) -> DPP wave reduce (VALU) -> lane63
// writes 1 float -> ONE barrier -> ds_read_b128 broadcast of 4 partials ->
// rcp -> update m/z. Noise prefetched 4 iterations deep (A/B/C/D register
// buffers, all statically indexed). State persists in d_ws across chunks.
__global__ __launch_bounds__(256) void scan_kernel(
    const float* __restrict__ nbuf, int T,
    const float* __restrict__ msrc, float* __restrict__ mdst,
    float* __restrict__ zst, float* __restrict__ zout,
    int first, int last)
{
  const int tid = threadIdx.x;            // 0..255
  const int row = blockIdx.x;             // 0..127
  const int wid = tid >> 6, lane = tid & 63;
  __shared__ __align__(16) float s_sum[2][4];   // [parity][wave]
  const float cc = 2.8853900817779268f;   // 2*log2(e)
  const size_t off = (size_t)row * 2048 + tid * 8;

  float m0, m1, m2, m3, m4, m5, m6, m7;
  float z0, z1, z2, z3, z4, z5, z6, z7;
  {
    float4 a = *(const float4*)(msrc + off);
    float4 b = *(const float4*)(msrc + off + 4);
    m0 = a.x; m1 = a.y; m2 = a.z; m3 = a.w;
    m4 = b.x; m5 = b.y; m6 = b.z; m7 = b.w;
  }
  if (first) {
    z0 = z1 = z2 = z3 = z4 = z5 = z6 = z7 = 0.f;
  } else {
    float4 a = *(const float4*)(zst + off);
    float4 b = *(const float4*)(zst + off + 4);
    z0 = a.x; z1 = a.y; z2 = a.z; z3 = a.w;
    z4 = b.x; z5 = b.y; z6 = b.z; z7 = b.w;
  }

  const float* nrow = nbuf + off;         // +262144 floats per iteration
  float4 A0, A1, B0, B1, C0, C1, D0, D1;
  { const float4* q = (const float4*)(nrow);                      A0 = q[0]; A1 = q[1]; }
  { const float4* q = (const float4*)(nrow + 262144);             B0 = q[0]; B1 = q[1]; }
  { const float4* q = (const float4*)(nrow + 2 * 262144);         C0 = q[0]; C1 = q[1]; }
  { const float4* q = (const float4*)(nrow + 3 * 262144);         D0 = q[0]; D1 = q[1]; }

#define STEP(N0, N1, KK, SLOT)                                               \
  {                                                                          \
    float e0 = EXP2F(fmaf(m0, cc, N0.x)), e1 = EXP2F(fmaf(m1, cc, N0.y));    \
    float e2 = EXP2F(fmaf(m2, cc, N0.z)), e3 = EXP2F(fmaf(m3, cc, N0.w));    \
    float e4 = EXP2F(fmaf(m4, cc, N1.x)), e5 = EXP2F(fmaf(m5, cc, N1.y));    \
    float e6 = EXP2F(fmaf(m6, cc, N1.z)), e7 = EXP2F(fmaf(m7, cc, N1.w));    \
    float p = ((e0 + e1) + (e2 + e3)) + ((e4 + e5) + (e6 + e7));             \
    p = wave_sum_dpp(p);                                                     \
    if (lane == 63) s_sum[SLOT][wid] = p;                                    \
    if ((KK) + 4 < T) {                                                      \
      const float4* q = (const float4*)(nrow + (size_t)((KK) + 4) * 262144); \
      N0 = q[0]; N1 = q[1];                                                  \
    }                                                                        \
    __syncthreads();                                                         \
    float4 sv = *(const float4*)&s_sum[SLOT][0];                             \
    float r = RCPF((sv.x + sv.y) + (sv.z + sv.w));                           \
    m0 = e0 * r; m1 = e1 * r; m2 = e2 * r; m3 = e3 * r;                      \
    m4 = e4 * r; m5 = e5 * r; m6 = e6 * r; m7 = e7 * r;                      \
    z0 = fmaxf(z0, m0); z1 = fmaxf(z1, m1);                                  \
    z2 = fmaxf(z2, m2); z3 = fmaxf(z3, m3);                                  \
    z4 = fmaxf(z4, m4); z5 = fmaxf(z5, m5);                                  \
    z6 = fmaxf(z6, m6); z7 = fmaxf(z7, m7);                                  \
  }

  for (int kk = 0; kk < T; kk += 4) {
    STEP(A0, A1, kk + 0, 0)
    STEP(B0, B1, kk + 1, 1)
    STEP(C0, C1, kk + 2, 0)
    STEP(D0, D1, kk + 3, 1)
  }
#undef STEP

  if (last) {
    *(float4*)(zout + off)     = make_float4(z0, z1, z2, z3);
    *(float4*)(zout + off + 4) = make_float4(z4, z5, z6, z7);
  } else {
    *(float4*)(mdst + off)     = make_float4(m0, m1, m2, m3);
    *(float4*)(mdst + off + 4) = make_float4(m4, m5, m6, m7);
    *(float4*)(zst + off)      = make_float4(z0, z1, z2, z3);
    *(float4*)(zst + off + 4)  = make_float4(z4, z5, z6, z7);
  }
}

// ------------------------------- launch ------------------------------------
extern "C" void kernel_launch(void* const* d_in, const int* in_sizes, int n_in,
                              void* d_out, int out_size, void* d_ws, size_t ws_size,
                              hipStream_t stream)
{
  const float* f   = (const float*)d_in[0];
  const float* w1  = (const float*)d_in[1];
  const float* b1  = (const float*)d_in[2];
  const float* g1  = (const float*)d_in[3];
  const float* be1 = (const float*)d_in[4];
  const float* w2  = (const float*)d_in[5];
  const float* b2  = (const float*)d_in[6];
  const float* g2  = (const float*)d_in[7];
  const float* be2 = (const float*)d_in[8];
  const float* w3  = (const float*)d_in[9];
  const float* b3  = (const float*)d_in[10];
  float* out = (float*)d_out;

  // ws layout (floats): h1 (4MB) | h2 (4MB) | logits (1MB) | P (noise window)
  float* h1     = (float*)d_ws;
  float* h2     = h1 + 1048576;
  float* logits = h2 + 1048576;
  float* P      = logits + 262144;

  const size_t need_big = (size_t)(2359296 + 8388608) * 4;
  const int s12 = (ws_size >= need_big) ? 8 : 4;
  const int s3  = (ws_size >= need_big) ? 32 : 16;

  dim3 blk(256);
  // layer 1: (128,2048) @ (8192,2048)^T
  gemm_splitk<<<dim3(64, s12), blk, 0, stream>>>(f, w1, P, 2048, 8192, 2048 / s12);
  bn_kernel<64><<<dim3(128), blk, 0, stream>>>(P, s12, 8192, b1, g1, be1, h1, 1);
  // layer 2: (128,8192) @ (8192,8192)^T
  gemm_splitk<<<dim3(64, s12), blk, 0, stream>>>(h1, w2, P, 8192, 8192, 8192 / s12);
  bn_kernel<64><<<dim3(128), blk, 0, stream>>>(P, s12, 8192, b2, g2, be2, h2, 1);
  // layer 3: (128,8192) @ (2048,8192)^T, BN no affine
  gemm_splitk<<<dim3(16, s3), blk, 0, stream>>>(h2, w3, P, 8192, 2048, 8192 / s3);
  bn_kernel<32><<<dim3(64), blk, 0, stream>>>(P, s3, 2048, b3, nullptr, nullptr, logits, 0);

  // ---- gumbel scan, chunked producer/consumer ----
  float* mstate = h1;             // 262144 floats (h1 dead after gemm2)
  float* zstate = h1 + 262144;    // 262144 floats
  float* nbuf   = P;              // P.. end of ws (dead after bn3)
  size_t avail_f = ws_size / 4 - 2359296;
  int T = (int)(avail_f / 262144);
  if (T > 1024) T = 1024;
  T &= ~3;                        // multiple of 4 (scan unrolls 4-deep)
  for (int k0 = 0; k0 < 1024; ) {
    int t = T; if (t > 1024 - k0) t = 1024 - k0;
    t &= ~3;
    noise_kernel<<<dim3(t * 128), dim3(256), 0, stream>>>(nbuf, k0, t);
    const int first = (k0 == 0);
    const int lastc = (k0 + t >= 1024);
    scan_kernel<<<dim3(128), dim3(256), 0, stream>>>(
        nbuf, t, first ? logits : mstate, mstate, zstate, out, first, lastc);
    k0 += t;
  }
}